// Round 8
// baseline (650.572 us; speedup 1.0000x reference)
//
#include <hip/hip_runtime.h>
#include <hip/hip_bf16.h>
#include <math.h>

// ---------------------------------------------------------------------------
// Quantized CNN forward (bitwise-exact vs fp32 reference):
//   block_k: maxpool2( quant_act( conv3x3(x, quant_weight(wk)), ak ) )
//   then global max over HxW, then 1x1 conv (10x128).
// quant_act is monotone => commutes with maxpool (pool raw conv, quantize once).
//
// Sparse formulation (R7, absmax 0.0): ternary weights are ~96% zero; skipping
// zero-weight FMAs is bitwise-safe, nonzeros applied in (ci asc, k asc) order.
//
// R8: R7 was latency-serial (VALUBusy 11%): per-co entry loops are dependent
// chains (s_load -> ds_read ~120cyc -> fma), executed sequentially for 16 co.
// Fix: SLOT-MAJOR padded CSR — per chunk, pad each co's list to the chunk max
// Ls with {off=0, coef=0.0f} (fma(+0,v,acc) only perturbs zero signs; all
// downstream diffs remain |0|). Layout E[slot][co] => per uniform slot, the
// unrolled co=0..15 body issues 32 independent LDS reads + 64 FMAs (ILP ~16x).
// Staging uses flat tid+256*s slots (conflict-free ds_writes).
// ---------------------------------------------------------------------------

__global__ __launch_bounds__(64)
void prep_zero(unsigned* __restrict__ maxb) {
    if (threadIdx.x < 4) maxb[threadIdx.x] = 0u;
}

__global__ __launch_bounds__(256)
void prep_absmax(const float* __restrict__ w1, const float* __restrict__ w2,
                 const float* __restrict__ w3, const float* __restrict__ wc,
                 unsigned* __restrict__ maxb) {
    const float* srcs[4] = {w1, w2, w3, wc};
    const int    ns[4]   = {32*3*9, 64*32*9, 128*64*9, 10*128};
    const int t = blockIdx.y;
    const float* s = srcs[t];
    const int    N = ns[t];
    float m = 0.f;
    for (int i = blockIdx.x * 256 + threadIdx.x; i < N; i += 16 * 256)
        m = fmaxf(m, fabsf(s[i]));
    #pragma unroll
    for (int o = 32; o > 0; o >>= 1) m = fmaxf(m, __shfl_down(m, o));
    __shared__ float red[4];
    const int lane = threadIdx.x & 63, wid = threadIdx.x >> 6;
    if (lane == 0) red[wid] = m;
    __syncthreads();
    if (threadIdx.x == 0) {
        float mm = fmaxf(fmaxf(red[0], red[1]), fmaxf(red[2], red[3]));
        atomicMax(maxb + t, __float_as_uint(mm));  // |w|>=0: uint order == float order
    }
}

__global__ __launch_bounds__(256)
void prep_quant(const float* __restrict__ w1, const float* __restrict__ w2,
                const float* __restrict__ w3, const float* __restrict__ wc,
                const unsigned* __restrict__ maxb,
                float* __restrict__ q1, float* __restrict__ q2,
                float* __restrict__ q3, float* __restrict__ qc) {
    const float* srcs[4] = {w1, w2, w3, wc};
    float*       dsts[4] = {q1, q2, q3, qc};
    const int    ns[4]   = {32*3*9, 64*32*9, 128*64*9, 10*128};
    const int t = blockIdx.y;
    const float* s = srcs[t];
    float*       d = dsts[t];
    const int    N = ns[t];
    const float sc = fmaxf(__uint_as_float(maxb[t]), 1e-8f);  // qmax = 2^(2-1)-1 = 1
    for (int i = blockIdx.x * 256 + threadIdx.x; i < N; i += 16 * 256)
        d[i] = rintf(s[i] / sc) * sc;
}

// Build slot-major padded CSR. Per (co, ci-chunk-of-8): nonzeros in
// (ci asc, k asc) order; chunk slot count Ls[ch] = max over co; pads {0,0}.
// E[(lb[ch]+s)*Co + co] = { (ci-ch*8)*1156 + ky*34 + kx , float_bits(w) }.
// lbase[ch] = cumulative slot base (nchunk+1 entries). One block per layer.
__global__ __launch_bounds__(256)
void build_csr_t(const float* __restrict__ qw, int Co, int CIN,
                 int* __restrict__ lbase, int2* __restrict__ E) {
    const int nchunk = (CIN + 7) / 8;
    const int nrows = Co * nchunk;
    __shared__ int cnt[1024];
    __shared__ int Ls[8];
    __shared__ int lb[9];
    const int t = threadIdx.x;
    for (int rc = t; rc < nrows; rc += 256) {
        const int co = rc / nchunk, ch = rc - co * nchunk;
        const int c0 = ch * 8, c1 = min(CIN, c0 + 8);
        int n = 0;
        for (int ci = c0; ci < c1; ++ci)
            for (int k = 0; k < 9; ++k)
                if (qw[(co * CIN + ci) * 9 + k] != 0.f) ++n;
        cnt[rc] = n;
    }
    __syncthreads();
    if (t < nchunk) {
        int m = 0;
        for (int co = 0; co < Co; ++co) m = max(m, cnt[co * nchunk + t]);
        Ls[t] = m;
    }
    __syncthreads();
    if (t == 0) {
        int s = 0;
        for (int ch = 0; ch < nchunk; ++ch) { lb[ch] = s; s += Ls[ch]; }
        lb[nchunk] = s;
        for (int ch = 0; ch <= nchunk; ++ch) lbase[ch] = lb[ch];
    }
    __syncthreads();
    for (int rc = t; rc < nrows; rc += 256) {
        const int co = rc / nchunk, ch = rc - co * nchunk;
        const int c0 = ch * 8, c1 = min(CIN, c0 + 8);
        int pos = 0;
        for (int ci = c0; ci < c1; ++ci)
            for (int k = 0; k < 9; ++k) {
                const float w = qw[(co * CIN + ci) * 9 + k];
                if (w != 0.f) {
                    E[(size_t)(lb[ch] + pos) * Co + co] =
                        make_int2((ci - c0) * 1156 + (k / 3) * 34 + (k % 3),
                                  __float_as_int(w));
                    ++pos;
                }
            }
        for (; pos < Ls[ch]; ++pos)
            E[(size_t)(lb[ch] + pos) * Co + co] = make_int2(0, 0);
    }
}

// Sparse fused conv3x3(pad=1) + maxpool2 + quant_act.
// 16x16 threads over a 16x16 pooled tile (32x32 conv px, 34x34 input tile).
// ci in chunks of 8 staged flat (slots tid+256*s, conflict-free writes).
// Compute: per uniform slot s, unrolled co=0..NCO-1 -> 16 independent chains.
template<int CIN, int Co, int NCO>
__global__ __launch_bounds__(256, 4)
void conv_sparse(const float* __restrict__ in, const int* __restrict__ lbase,
                 const int2* __restrict__ E,
                 const float* __restrict__ alpha_p, float* __restrict__ out,
                 int H, int W) {
    constexpr int NCHUNK = (CIN + 7) / 8;
    constexpr int CCH    = (CIN < 8) ? CIN : 8;
    constexpr int NGRP   = Co / NCO;
    const int PH = H >> 1, PW = W >> 1;
    const int tx = threadIdx.x, ty = threadIdx.y;
    const int tid = ty * 16 + tx;
    const int b   = blockIdx.z / NGRP;
    const int co0 = (blockIdx.z % NGRP) * NCO;
    const int px  = blockIdx.x * 16 + tx;
    const int py  = blockIdx.y * 16 + ty;
    const int ix0 = blockIdx.x * 32 - 1;
    const int iy0 = blockIdx.y * 32 - 1;

    __shared__ float tile[CCH * 1156];           // chunk-local [ci][34*34] flat
    const size_t HW = (size_t)H * W;
    const float* inB = in + (size_t)b * CIN * HW;

    // Flat staging slots hoisted once; -1 = zero-fill (pad / out of image).
    int sidx[5];
    #pragma unroll
    for (int s = 0; s < 5; ++s) {
        const int idx = tid + 256 * s;
        const int r = idx / 34, c = idx - r * 34;
        const int gy = iy0 + r, gx = ix0 + c;
        sidx[s] = (idx < 1156 && gy >= 0 && gy < H && gx >= 0 && gx < W)
                  ? (gy * W + gx) : -1;
    }

    float acc[NCO][4];
    #pragma unroll
    for (int c = 0; c < NCO; ++c)
        #pragma unroll
        for (int p = 0; p < 4; ++p) acc[c][p] = 0.f;

    const int base = (2 * ty) * 34 + 2 * tx;     // word offset of thread's patch

    for (int chunk = 0; chunk < NCHUNK; ++chunk) {
        if (chunk) __syncthreads();               // protect previous compute
        const int ch0 = chunk * 8;
        #pragma unroll
        for (int ch = 0; ch < CCH; ++ch) {
            const float* inC = inB + (size_t)(ch0 + ch) * HW;
            #pragma unroll
            for (int s = 0; s < 5; ++s) {
                const int idx = tid + 256 * s;    // imm-offset ds_write
                if (s < 4 || idx < 1156) {
                    const int g = sidx[s];
                    float v = 0.f;
                    if (g >= 0) v = inC[g];
                    tile[ch * 1156 + idx] = v;
                }
            }
        }
        __syncthreads();

        const int s1 = lbase[chunk + 1];          // uniform -> scalar
        for (int s = lbase[chunk]; s < s1; ++s) {
            const int2* ep = E + (size_t)s * Co + co0;
            #pragma unroll
            for (int c = 0; c < NCO; ++c) {
                const int2 e = ep[c];             // uniform (128B batch/slot)
                const float coef = __int_as_float(e.y);
                const float* tp = tile + e.x + base;
                acc[c][0] = fmaf(coef, tp[0],  acc[c][0]);
                acc[c][1] = fmaf(coef, tp[1],  acc[c][1]);
                acc[c][2] = fmaf(coef, tp[34], acc[c][2]);
                acc[c][3] = fmaf(coef, tp[35], acc[c][3]);
            }
        }
    }

    if (py < PH && px < PW) {
        const float alpha = *alpha_p;
        const float scale = alpha / 3.0f;         // 2^ABITS - 1 = 3
        #pragma unroll
        for (int c = 0; c < NCO; ++c) {
            const float m = fmaxf(fmaxf(acc[c][0], acc[c][1]),
                                  fmaxf(acc[c][2], acc[c][3]));
            const float y = fminf(fmaxf(m, 0.f), alpha);
            out[(((size_t)b * Co + co0 + c) * PH + py) * PW + px] =
                rintf(y / scale) * scale;
        }
    }
}

// One wave per (channel, batch): global max over 28x28.
__global__ __launch_bounds__(64)
void gmax_kernel(const float* __restrict__ h3, float* __restrict__ g) {
    const int c = blockIdx.x, b = blockIdx.y;
    const float* p = h3 + ((size_t)b * 128 + c) * 784;
    float m = -INFINITY;
    for (int i = threadIdx.x; i < 784; i += 64) m = fmaxf(m, p[i]);
    #pragma unroll
    for (int o = 32; o > 0; o >>= 1) m = fmaxf(m, __shfl_down(m, o));
    if (threadIdx.x == 0) g[b * 128 + c] = m;
}

// 1x1 conv 128->10 per batch (same k-ascending FMA order as round 1).
__global__ __launch_bounds__(128)
void classify_kernel(const float* __restrict__ g, const float* __restrict__ qwc,
                     float* __restrict__ out) {
    const int b = blockIdx.x;
    __shared__ float gg[128];
    gg[threadIdx.x] = g[b * 128 + threadIdx.x];
    __syncthreads();
    if (threadIdx.x < 10) {
        float s = 0.f;
        for (int k = 0; k < 128; ++k) s += qwc[threadIdx.x * 128 + k] * gg[k];
        out[b * 10 + threadIdx.x] = s;
    }
}

extern "C" void kernel_launch(void* const* d_in, const int* in_sizes, int n_in,
                              void* d_out, int out_size, void* d_ws, size_t ws_size,
                              hipStream_t stream) {
    const float* x  = (const float*)d_in[0];
    const float* w1 = (const float*)d_in[1];
    const float* w2 = (const float*)d_in[2];
    const float* w3 = (const float*)d_in[3];
    const float* wc = (const float*)d_in[4];
    const float* a1 = (const float*)d_in[5];
    const float* a2 = (const float*)d_in[6];
    const float* a3 = (const float*)d_in[7];

    float* ws = (float*)d_ws;
    size_t o = 0;
    float* qw1 = ws + o; o += 32 * 3 * 9;
    float* qw2 = ws + o; o += 64 * 32 * 9;
    float* qw3 = ws + o; o += 73728;                // 128*64*9
    float* qwc = ws + o; o += 10 * 128;             // -> o even so far
    unsigned* maxb = (unsigned*)(ws + o); o += 4;
    float* g   = ws + o; o += 32 * 128;
    int*   lb1 = (int*)(ws + o); o += 16;
    int*   lb2 = (int*)(ws + o); o += 16;
    int*   lb3 = (int*)(ws + o); o += 16;           // o still even
    int2*  E1  = (int2*)(ws + o); o += 2UL * 864;   // worst case: all nnz
    int2*  E2  = (int2*)(ws + o); o += 2UL * 18432;
    int2*  E3  = (int2*)(ws + o); o += 2UL * 73728;
    float* h1p = ws + o; o += 32UL * 32 * 112 * 112;
    float* h2p = ws + o; o += 32UL * 64 * 56 * 56;
    float* h3p = ws + o; o += 32UL * 128 * 28 * 28;

    prep_zero<<<1, 64, 0, stream>>>(maxb);
    prep_absmax<<<dim3(16, 4), 256, 0, stream>>>(w1, w2, w3, wc, maxb);
    prep_quant<<<dim3(16, 4), 256, 0, stream>>>(w1, w2, w3, wc, maxb,
                                                qw1, qw2, qw3, qwc);
    build_csr_t<<<1, 256, 0, stream>>>(qw1, 32, 3,  lb1, E1);
    build_csr_t<<<1, 256, 0, stream>>>(qw2, 64, 32, lb2, E2);
    build_csr_t<<<1, 256, 0, stream>>>(qw3, 128, 64, lb3, E3);

    // conv1: 3->32, 224x224 -> pooled 112x112. tiles 7x7, z = 32b * 2 grp
    conv_sparse<3, 32, 16><<<dim3(7, 7, 32 * 2), dim3(16, 16), 0, stream>>>(
        x, lb1, E1, a1, h1p, 224, 224);
    // conv2: 32->64, pooled 56x56. tiles 4x4, z = 32b * 4 grp
    conv_sparse<32, 64, 16><<<dim3(4, 4, 32 * 4), dim3(16, 16), 0, stream>>>(
        h1p, lb2, E2, a2, h2p, 112, 112);
    // conv3: 64->128, pooled 28x28. tiles 2x2, z = 32b * 8 grp
    conv_sparse<64, 128, 16><<<dim3(2, 2, 32 * 8), dim3(16, 16), 0, stream>>>(
        h2p, lb3, E3, a3, h3p, 56, 56);

    gmax_kernel<<<dim3(128, 32), 64, 0, stream>>>(h3p, g);
    classify_kernel<<<32, 128, 0, stream>>>(g, qwc, (float*)d_out);
}

// Round 9
// 548.378 us; speedup vs baseline: 1.1864x; 1.1864x over previous
//
#include <hip/hip_runtime.h>
#include <hip/hip_bf16.h>
#include <math.h>

// ---------------------------------------------------------------------------
// Quantized CNN forward (bitwise-exact vs fp32 reference):
//   block_k: maxpool2( quant_act( conv3x3(x, quant_weight(wk)), ak ) )
//   then global max over HxW, then 1x1 conv (10x128).
// Sparse formulation (R7, absmax 0.0): ternary weights ~96% zero; zero-weight
// FMAs are skippable bitwise-safely; nonzeros applied (ci asc, k asc) per co.
//
// R9: R8's slot-major padding inflated work 3x (pad-to-max over ALL co, and
// lbase used the global max). LDS-read-throughput bound (16.8M ds_read x 5.8cy
// x 1.58 / 256CU ~ 250us ~ measured 219us). Fix: sort co by nnz, group 16
// similar-length lists (inflation ->~1.2x), per-(group,chunk) slot counts,
// epilogue writes through cperm. Pad {0,+0.0f} (acc never -0 => bitwise-safe).
// ---------------------------------------------------------------------------

__global__ __launch_bounds__(64)
void prep_zero(unsigned* __restrict__ maxb) {
    if (threadIdx.x < 4) maxb[threadIdx.x] = 0u;
}

__global__ __launch_bounds__(256)
void prep_absmax(const float* __restrict__ w1, const float* __restrict__ w2,
                 const float* __restrict__ w3, const float* __restrict__ wc,
                 unsigned* __restrict__ maxb) {
    const float* srcs[4] = {w1, w2, w3, wc};
    const int    ns[4]   = {32*3*9, 64*32*9, 128*64*9, 10*128};
    const int t = blockIdx.y;
    const float* s = srcs[t];
    const int    N = ns[t];
    float m = 0.f;
    for (int i = blockIdx.x * 256 + threadIdx.x; i < N; i += 16 * 256)
        m = fmaxf(m, fabsf(s[i]));
    #pragma unroll
    for (int o = 32; o > 0; o >>= 1) m = fmaxf(m, __shfl_down(m, o));
    __shared__ float red[4];
    const int lane = threadIdx.x & 63, wid = threadIdx.x >> 6;
    if (lane == 0) red[wid] = m;
    __syncthreads();
    if (threadIdx.x == 0) {
        float mm = fmaxf(fmaxf(red[0], red[1]), fmaxf(red[2], red[3]));
        atomicMax(maxb + t, __float_as_uint(mm));  // |w|>=0: uint order == float order
    }
}

__global__ __launch_bounds__(256)
void prep_quant(const float* __restrict__ w1, const float* __restrict__ w2,
                const float* __restrict__ w3, const float* __restrict__ wc,
                const unsigned* __restrict__ maxb,
                float* __restrict__ q1, float* __restrict__ q2,
                float* __restrict__ q3, float* __restrict__ qc) {
    const float* srcs[4] = {w1, w2, w3, wc};
    float*       dsts[4] = {q1, q2, q3, qc};
    const int    ns[4]   = {32*3*9, 64*32*9, 128*64*9, 10*128};
    const int t = blockIdx.y;
    const float* s = srcs[t];
    float*       d = dsts[t];
    const int    N = ns[t];
    const float sc = fmaxf(__uint_as_float(maxb[t]), 1e-8f);  // qmax = 2^(2-1)-1 = 1
    for (int i = blockIdx.x * 256 + threadIdx.x; i < N; i += 16 * 256)
        d[i] = rintf(s[i] / sc) * sc;
}

// Sorted slot-major padded CSR. co sorted by (total nnz, co); groups of 16
// consecutive sorted channels share a block. Per (group, chunk-of-8-ci):
// slots = max nnz within the group; entries (ci asc, k asc) per co; pads
// {0, +0.0f}. E[slot*16 + c] with slot global; lbase[g*(nchunk+1)+ch] bases.
// cperm[pos] = original channel at sorted position pos. One block per layer.
__global__ __launch_bounds__(256)
void build_csr_s(const float* __restrict__ qw, int Co, int CIN,
                 int* __restrict__ lbase, int* __restrict__ cperm,
                 int2* __restrict__ E) {
    const int nchunk = (CIN + 7) / 8;
    const int ngrp = Co / 16;
    __shared__ int cnt[1024];     // [orig co][ch]
    __shared__ int tot[128];
    __shared__ int perm[128];
    __shared__ int Ls[64];        // [g][ch] group max
    const int t = threadIdx.x;
    const int nrows = Co * nchunk;

    for (int rc = t; rc < nrows; rc += 256) {
        const int co = rc / nchunk, ch = rc - co * nchunk;
        const int c0 = ch * 8, c1 = min(CIN, c0 + 8);
        int n = 0;
        for (int ci = c0; ci < c1; ++ci)
            for (int k = 0; k < 9; ++k)
                if (qw[(co * CIN + ci) * 9 + k] != 0.f) ++n;
        cnt[rc] = n;
    }
    __syncthreads();
    if (t < Co) {
        int s = 0;
        for (int ch = 0; ch < nchunk; ++ch) s += cnt[t * nchunk + ch];
        tot[t] = s;
    }
    __syncthreads();
    if (t < Co) {               // deterministic rank sort by (tot, co)
        int r = 0;
        for (int j = 0; j < Co; ++j)
            r += (tot[j] < tot[t]) || (tot[j] == tot[t] && j < t);
        perm[r] = t;
    }
    __syncthreads();
    if (t < ngrp * nchunk) {
        const int g = t / nchunk, ch = t - g * nchunk;
        int m = 0;
        for (int c = 0; c < 16; ++c)
            m = max(m, cnt[perm[g * 16 + c] * nchunk + ch]);
        Ls[t] = m;
    }
    __syncthreads();
    if (t == 0) {
        int acc = 0;
        for (int g = 0; g < ngrp; ++g) {
            for (int ch = 0; ch < nchunk; ++ch) {
                lbase[g * (nchunk + 1) + ch] = acc;
                acc += Ls[g * nchunk + ch];
            }
            lbase[g * (nchunk + 1) + nchunk] = acc;
        }
    }
    if (t < Co) cperm[t] = perm[t];
    __syncthreads();             // orders the global lbase writes for emit

    for (int rc = t; rc < nrows; rc += 256) {
        const int idx = rc / nchunk, ch = rc - idx * nchunk;
        const int g = idx >> 4, c = idx & 15;
        const int co = perm[idx];
        const int c0 = ch * 8, c1 = min(CIN, c0 + 8);
        int pos = lbase[g * (nchunk + 1) + ch];
        const int pend = lbase[g * (nchunk + 1) + ch + 1];
        for (int ci = c0; ci < c1; ++ci)
            for (int k = 0; k < 9; ++k) {
                const float w = qw[(co * CIN + ci) * 9 + k];
                if (w != 0.f) {
                    E[(size_t)pos * 16 + c] =
                        make_int2((ci - c0) * 1156 + (k / 3) * 34 + (k % 3),
                                  __float_as_int(w));
                    ++pos;
                }
            }
        for (; pos < pend; ++pos)
            E[(size_t)pos * 16 + c] = make_int2(0, 0);
    }
}

// Sparse fused conv3x3(pad=1) + maxpool2 + quant_act.
// 16x16 threads over a 16x16 pooled tile (32x32 conv px, 34x34 input tile).
// ci in chunks of 8 staged flat (slots tid+256*s, conflict-free writes).
// Per uniform slot, unrolled c=0..15 -> 16 independent LDS-read/FMA chains.
template<int CIN, int Co>
__global__ __launch_bounds__(256, 4)
void conv_sparse(const float* __restrict__ in, const int* __restrict__ lbase,
                 const int* __restrict__ cperm, const int2* __restrict__ E,
                 const float* __restrict__ alpha_p, float* __restrict__ out,
                 int H, int W) {
    constexpr int NCHUNK = (CIN + 7) / 8;
    constexpr int CCH    = (CIN < 8) ? CIN : 8;
    constexpr int NGRP   = Co / 16;
    const int PH = H >> 1, PW = W >> 1;
    const int tx = threadIdx.x, ty = threadIdx.y;
    const int tid = ty * 16 + tx;
    const int b   = blockIdx.z / NGRP;
    const int grp = blockIdx.z % NGRP;
    const int px  = blockIdx.x * 16 + tx;
    const int py  = blockIdx.y * 16 + ty;
    const int ix0 = blockIdx.x * 32 - 1;
    const int iy0 = blockIdx.y * 32 - 1;

    __shared__ float tile[CCH * 1156];           // chunk-local [ci][34*34] flat
    const size_t HW = (size_t)H * W;
    const float* inB = in + (size_t)b * CIN * HW;

    // Flat staging slots hoisted once; -1 = zero-fill (pad / out of image).
    int sidx[5];
    #pragma unroll
    for (int s = 0; s < 5; ++s) {
        const int idx = tid + 256 * s;
        const int r = idx / 34, c = idx - r * 34;
        const int gy = iy0 + r, gx = ix0 + c;
        sidx[s] = (idx < 1156 && gy >= 0 && gy < H && gx >= 0 && gx < W)
                  ? (gy * W + gx) : -1;
    }

    float acc[16][4];
    #pragma unroll
    for (int c = 0; c < 16; ++c)
        #pragma unroll
        for (int p = 0; p < 4; ++p) acc[c][p] = 0.f;

    const int base = (2 * ty) * 34 + 2 * tx;     // word offset of thread's patch

    for (int chunk = 0; chunk < NCHUNK; ++chunk) {
        if (chunk) __syncthreads();               // protect previous compute
        const int ch0 = chunk * 8;
        #pragma unroll
        for (int ch = 0; ch < CCH; ++ch) {
            const float* inC = inB + (size_t)(ch0 + ch) * HW;
            #pragma unroll
            for (int s = 0; s < 5; ++s) {
                const int idx = tid + 256 * s;    // imm-offset ds_write
                if (s < 4 || idx < 1156) {
                    const int g = sidx[s];
                    float v = 0.f;
                    if (g >= 0) v = inC[g];
                    tile[ch * 1156 + idx] = v;
                }
            }
        }
        __syncthreads();

        const int lb0 = lbase[grp * (NCHUNK + 1) + chunk];   // uniform -> scalar
        const int lb1 = lbase[grp * (NCHUNK + 1) + chunk + 1];
        #pragma unroll 2
        for (int s = lb0; s < lb1; ++s) {
            const int2* ep = E + (size_t)s * 16;
            #pragma unroll
            for (int c = 0; c < 16; ++c) {
                const int2 e = ep[c];             // uniform (128B batch/slot)
                const float coef = __int_as_float(e.y);
                const float* tp = tile + e.x + base;
                acc[c][0] = fmaf(coef, tp[0],  acc[c][0]);
                acc[c][1] = fmaf(coef, tp[1],  acc[c][1]);
                acc[c][2] = fmaf(coef, tp[34], acc[c][2]);
                acc[c][3] = fmaf(coef, tp[35], acc[c][3]);
            }
        }
    }

    if (py < PH && px < PW) {
        const float alpha = *alpha_p;
        const float scale = alpha / 3.0f;         // 2^ABITS - 1 = 3
        #pragma unroll
        for (int c = 0; c < 16; ++c) {
            const int co = cperm[grp * 16 + c];   // sorted slot -> orig channel
            const float m = fmaxf(fmaxf(acc[c][0], acc[c][1]),
                                  fmaxf(acc[c][2], acc[c][3]));
            const float y = fminf(fmaxf(m, 0.f), alpha);
            out[(((size_t)b * Co + co) * PH + py) * PW + px] =
                rintf(y / scale) * scale;
        }
    }
}

// One wave per (channel, batch): global max over 28x28.
__global__ __launch_bounds__(64)
void gmax_kernel(const float* __restrict__ h3, float* __restrict__ g) {
    const int c = blockIdx.x, b = blockIdx.y;
    const float* p = h3 + ((size_t)b * 128 + c) * 784;
    float m = -INFINITY;
    for (int i = threadIdx.x; i < 784; i += 64) m = fmaxf(m, p[i]);
    #pragma unroll
    for (int o = 32; o > 0; o >>= 1) m = fmaxf(m, __shfl_down(m, o));
    if (threadIdx.x == 0) g[b * 128 + c] = m;
}

// 1x1 conv 128->10 per batch (same k-ascending FMA order as round 1).
__global__ __launch_bounds__(128)
void classify_kernel(const float* __restrict__ g, const float* __restrict__ qwc,
                     float* __restrict__ out) {
    const int b = blockIdx.x;
    __shared__ float gg[128];
    gg[threadIdx.x] = g[b * 128 + threadIdx.x];
    __syncthreads();
    if (threadIdx.x < 10) {
        float s = 0.f;
        for (int k = 0; k < 128; ++k) s += qwc[threadIdx.x * 128 + k] * gg[k];
        out[b * 10 + threadIdx.x] = s;
    }
}

extern "C" void kernel_launch(void* const* d_in, const int* in_sizes, int n_in,
                              void* d_out, int out_size, void* d_ws, size_t ws_size,
                              hipStream_t stream) {
    const float* x  = (const float*)d_in[0];
    const float* w1 = (const float*)d_in[1];
    const float* w2 = (const float*)d_in[2];
    const float* w3 = (const float*)d_in[3];
    const float* wc = (const float*)d_in[4];
    const float* a1 = (const float*)d_in[5];
    const float* a2 = (const float*)d_in[6];
    const float* a3 = (const float*)d_in[7];

    float* ws = (float*)d_ws;
    size_t o = 0;
    float* qw1 = ws + o; o += 32 * 3 * 9;
    float* qw2 = ws + o; o += 64 * 32 * 9;
    float* qw3 = ws + o; o += 73728;                // 128*64*9
    float* qwc = ws + o; o += 10 * 128;
    unsigned* maxb = (unsigned*)(ws + o); o += 4;
    float* g   = ws + o; o += 32 * 128;
    int*   lb1 = (int*)(ws + o); o += 16;           // 2 grp * 2
    int*   lb2 = (int*)(ws + o); o += 32;           // 4 grp * 5
    int*   lb3 = (int*)(ws + o); o += 80;           // 8 grp * 9
    int*   cp1 = (int*)(ws + o); o += 32;
    int*   cp2 = (int*)(ws + o); o += 64;
    int*   cp3 = (int*)(ws + o); o += 128;          // o stays even
    int2*  E1  = (int2*)(ws + o); o += 2UL * 928;   // dense bound + pad
    int2*  E2  = (int2*)(ws + o); o += 2UL * 18496;
    int2*  E3  = (int2*)(ws + o); o += 2UL * 73792;
    float* h1p = ws + o; o += 32UL * 32 * 112 * 112;
    float* h2p = ws + o; o += 32UL * 64 * 56 * 56;
    float* h3p = ws + o; o += 32UL * 128 * 28 * 28;

    prep_zero<<<1, 64, 0, stream>>>(maxb);
    prep_absmax<<<dim3(16, 4), 256, 0, stream>>>(w1, w2, w3, wc, maxb);
    prep_quant<<<dim3(16, 4), 256, 0, stream>>>(w1, w2, w3, wc, maxb,
                                                qw1, qw2, qw3, qwc);
    build_csr_s<<<1, 256, 0, stream>>>(qw1, 32, 3,  lb1, cp1, E1);
    build_csr_s<<<1, 256, 0, stream>>>(qw2, 64, 32, lb2, cp2, E2);
    build_csr_s<<<1, 256, 0, stream>>>(qw3, 128, 64, lb3, cp3, E3);

    // conv1: 3->32, 224x224 -> pooled 112x112. tiles 7x7, z = 32b * 2 grp
    conv_sparse<3, 32><<<dim3(7, 7, 32 * 2), dim3(16, 16), 0, stream>>>(
        x, lb1, cp1, E1, a1, h1p, 224, 224);
    // conv2: 32->64, pooled 56x56. tiles 4x4, z = 32b * 4 grp
    conv_sparse<32, 64><<<dim3(4, 4, 32 * 4), dim3(16, 16), 0, stream>>>(
        h1p, lb2, cp2, E2, a2, h2p, 112, 112);
    // conv3: 64->128, pooled 28x28. tiles 2x2, z = 32b * 8 grp
    conv_sparse<64, 128><<<dim3(2, 2, 32 * 8), dim3(16, 16), 0, stream>>>(
        h2p, lb3, cp3, E3, a3, h3p, 56, 56);

    gmax_kernel<<<dim3(128, 32), 64, 0, stream>>>(h3p, g);
    classify_kernel<<<32, 128, 0, stream>>>(g, qwc, (float*)d_out);
}